// Round 8
// baseline (376.663 us; speedup 1.0000x reference)
//
#include <hip/hip_runtime.h>

#define BB 16
#define KD 128
#define ND 8000
#define DD 256
#define LMB 1000.0f

typedef __attribute__((ext_vector_type(8))) short bf16x8;
typedef __attribute__((ext_vector_type(4))) short bf16x4;
typedef __attribute__((ext_vector_type(4))) float f32x4;
typedef unsigned short ushort_t;

// exact split: x = hi + lo (hi = truncate-to-bf16, lo = RNE(x - hi))
__device__ __forceinline__ void split_bf16(float x, ushort_t& h, ushort_t& l) {
    unsigned int bi = __float_as_uint(x);
    h = (ushort_t)(bi >> 16);
    float lo = x - __uint_as_float(bi & 0xFFFF0000u);
    unsigned int lb = __float_as_uint(lo);
    lb = lb + 0x7FFFu + ((lb >> 16) & 1u);
    l = (ushort_t)(lb >> 16);
}

// two f32x4 (k=0..3, k=4..7) -> bf16 hi/lo fragments
__device__ __forceinline__ void cvt8(f32x4 a, f32x4 b, bf16x8& h, bf16x8& l) {
    #pragma unroll
    for (int j = 0; j < 4; ++j) {
        ushort_t hh, ll;
        split_bf16(a[j], hh, ll); h[j] = (short)hh; l[j] = (short)ll;
        split_bf16(b[j], hh, ll); h[4 + j] = (short)hh; l[4 + j] = (short)ll;
    }
}

// async global->LDS, 16B per lane, lds dest = uniform base + lane*16
__device__ __forceinline__ void gll16(const float* g, float* l) {
    __builtin_amdgcn_global_load_lds(
        (const __attribute__((address_space(1))) void*)g,
        (__attribute__((address_space(3))) void*)l, 16, 0, 0);
}

// ---------------- K1: projection  sd[b][k][d] = sum_n pinv[b][k][n]*descr[b][d][n]
// Raw-fp32 async staging (global_load_lds w16, double-buffered, counted vmcnt(3),
// raw s_barrier), conversion to split-bf16 in the MFMA phase. XOR-swizzled source
// (c4 = slot ^ (row&7)) + same XOR on ds_read (rule #21) -> conflict-free b128.
// grid (16 b, 2 which, 25 slices) = 800 blocks, 1024 thr = 16 waves (4x4),
// wave tile 32(k) x 64(d); 10 chunks x 32 n = 320 n/slice, no tail.
#define ROWS 384      // KD + DD
#define CHF 32        // chunk width in floats
#define NPS 320
#define NCHK 10
#define SBUF_FL 12288 // ROWS*CHF

__global__ __attribute__((amdgpu_flat_work_group_size(1024, 1024), amdgpu_waves_per_eu(2, 4)))
void proj_kernel(
    const float* __restrict__ pinv_a, const float* __restrict__ descr_a,
    const float* __restrict__ pinv_b, const float* __restrict__ descr_b,
    float* __restrict__ sd_a, float* __restrict__ sd_b)
{
    const int b = blockIdx.x, which = blockIdx.y, slice = blockIdx.z;
    const float* P  = (which ? pinv_b  : pinv_a)  + (size_t)b * KD * ND;
    const float* Dm = (which ? descr_b : descr_a) + (size_t)b * DD * ND;
    float* outp = (which ? sd_b : sd_a) + (size_t)b * KD * DD;

    __shared__ float Sbuf[2][SBUF_FL];

    const int tid = threadIdx.x;
    const int lane = tid & 63;
    const int wid = tid >> 6;                 // 0..15
    const int wm = wid >> 2, wn = wid & 3;    // wave tile: rows wm*32, cols wn*64
    const int fr = lane & 15;
    const int kg = lane >> 4;
    const int n0 = slice * NPS;

    // staging plan: 48 wave-instrs of 1KB; instr I = wid*3+u covers LDS rows [I*8, I*8+8)
    // lane: row = I*8 + (lane>>3), slot s = lane&7; global col-group c4 = s ^ (row&7)
    const float* gp[3];
    int lof[3];
    #pragma unroll
    for (int u = 0; u < 3; ++u) {
        int I = wid * 3 + u;
        int r = I * 8 + (lane >> 3);
        int c4 = (lane & 7) ^ (r & 7);
        const float* rowp = (r < KD) ? (P + (size_t)r * ND) : (Dm + (size_t)(r - KD) * ND);
        gp[u] = rowp + n0 + c4 * 4;
        lof[u] = I * 256;                     // float offset of this instr's 1KB window
    }

    f32x4 acc[2][4];
    #pragma unroll
    for (int i = 0; i < 2; ++i)
        #pragma unroll
        for (int j = 0; j < 4; ++j) acc[i][j] = (f32x4){0.f, 0.f, 0.f, 0.f};

    // prologue: stage chunk 0 -> buf 0
    #pragma unroll
    for (int u = 0; u < 3; ++u) gll16(gp[u], &Sbuf[0][lof[u]]);

    for (int t = 0; t < NCHK; ++t) {
        const int buf = t & 1;
        if (t + 1 < NCHK) {
            #pragma unroll
            for (int u = 0; u < 3; ++u) gll16(gp[u] + (t + 1) * CHF, &Sbuf[buf ^ 1][lof[u]]);
            __builtin_amdgcn_sched_barrier(0);
            asm volatile("s_waitcnt vmcnt(3)" ::: "memory");   // wait chunk t only
        } else {
            __builtin_amdgcn_sched_barrier(0);
            asm volatile("s_waitcnt vmcnt(0)" ::: "memory");
        }
        __builtin_amdgcn_sched_barrier(0);
        __builtin_amdgcn_s_barrier();
        __builtin_amdgcn_sched_barrier(0);

        const float* base = &Sbuf[buf][0];
        #pragma unroll
        for (int ni = 0; ni < 4; ++ni) {
            const int rB = KD + wn * 64 + ni * 16 + fr;
            const int rb7 = rB & 7;
            f32x4 b0 = *(const f32x4*)(base + rB * CHF + (((2 * kg)     ^ rb7) << 2));
            f32x4 b1 = *(const f32x4*)(base + rB * CHF + (((2 * kg + 1) ^ rb7) << 2));
            bf16x8 Bh, Bl;
            cvt8(b0, b1, Bh, Bl);
            #pragma unroll
            for (int mi = 0; mi < 2; ++mi) {
                const int rA = wm * 32 + mi * 16 + fr;
                const int ra7 = rA & 7;
                f32x4 a0 = *(const f32x4*)(base + rA * CHF + (((2 * kg)     ^ ra7) << 2));
                f32x4 a1 = *(const f32x4*)(base + rA * CHF + (((2 * kg + 1) ^ ra7) << 2));
                bf16x8 Ah, Al;
                cvt8(a0, a1, Ah, Al);
                acc[mi][ni] = __builtin_amdgcn_mfma_f32_16x16x32_bf16(Ah, Bh, acc[mi][ni], 0, 0, 0);
                acc[mi][ni] = __builtin_amdgcn_mfma_f32_16x16x32_bf16(Ah, Bl, acc[mi][ni], 0, 0, 0);
                acc[mi][ni] = __builtin_amdgcn_mfma_f32_16x16x32_bf16(Al, Bh, acc[mi][ni], 0, 0, 0);
            }
        }
        __builtin_amdgcn_sched_barrier(0);
        __builtin_amdgcn_s_barrier();
    }

    // epilogue: C/D layout col=lane&15, row=(lane>>4)*4+reg (m89)
    #pragma unroll
    for (int mi = 0; mi < 2; ++mi)
        #pragma unroll
        for (int ni = 0; ni < 4; ++ni) {
            int rbase = wm * 32 + mi * 16 + kg * 4;
            int ccol  = wn * 64 + ni * 16 + fr;
            #pragma unroll
            for (int r = 0; r < 4; ++r)
                atomicAdd(&outp[(size_t)(rbase + r) * DD + ccol], acc[mi][ni][r]);
        }
}

// ---------------- K2: masks (lambda folded in)
__global__ __launch_bounds__(256) void mask_kernel(
    const float* __restrict__ ea_g, const float* __restrict__ eb_g,
    float* __restrict__ lm_ab, float* __restrict__ lm_ba)
{
    const int b = blockIdx.x, tid = threadIdx.x;
    __shared__ float ta[KD], ua[KD], tb[KD], ub[KD];
    __shared__ float red[256];
    float e = (tid < KD) ? ea_g[b * KD + tid] : eb_g[b * KD + (tid - KD)];
    red[tid] = e;
    __syncthreads();
    for (int s = 128; s > 0; s >>= 1) {
        if (tid < s) red[tid] = fmaxf(red[tid], red[tid + s]);
        __syncthreads();
    }
    float is = 1.0f / red[0];
    float g = e * is;
    float den = 1.0f / (g * g + 1.0f);
    if (tid < KD) { ta[tid] = g * den; ua[tid] = den; }
    else          { tb[tid - KD] = g * den; ub[tid - KD] = den; }
    __syncthreads();
    for (int idx = tid; idx < KD * KD; idx += 256) {
        int i = idx >> 7, kc = idx & 127;
        float re = tb[i] - ta[kc], im = ub[i] - ua[kc];
        lm_ab[(size_t)b * KD * KD + idx] = LMB * (re * re + im * im);
        float re2 = ta[i] - tb[kc], im2 = ua[i] - ub[kc];
        lm_ba[(size_t)b * KD * KD + idx] = LMB * (re2 * re2 + im2 * im2);
    }
}

// ---------------- K3: Grams via split-bf16 MFMA, d-split for parallelism.
#define GSTR 68
__global__ __launch_bounds__(512, 2) void gram_kernel(
    const float* __restrict__ sd_a, const float* __restrict__ sd_b,
    float* __restrict__ AA)
{
    const int b = blockIdx.x, m = blockIdx.y, dchunk = blockIdx.z;
    const float* X = (m == 0) ? sd_a : sd_b;
    const float* Y = (m == 2) ? sd_a : X;
    X += (size_t)b * KD * DD;
    Y += (size_t)b * KD * DD;
    float* outp = AA + ((size_t)m * BB + b) * KD * KD;
    const int d0 = dchunk * 64;

    __shared__ ushort_t Xh[KD][GSTR], Xl[KD][GSTR];
    __shared__ ushort_t Yh[KD][GSTR], Yl[KD][GSTR];

    const int tid = threadIdx.x;
    const int lane = tid & 63;
    const int wid = tid >> 6;
    const int wm = wid >> 2, wn = wid & 3;
    const int fr = lane & 15;
    const int kg = lane >> 4;

    f32x4 acc[4][2];
    #pragma unroll
    for (int i = 0; i < 4; ++i)
        #pragma unroll
        for (int j = 0; j < 2; ++j) acc[i][j] = (f32x4){0.f, 0.f, 0.f, 0.f};

    #pragma unroll
    for (int u = 0; u < 8; ++u) {
        int idx = tid + (u & 3) * 512;
        int r = idx >> 4, c4 = idx & 15;
        const float* src = (u < 4) ? X : Y;
        float4 v = *(const float4*)(src + (size_t)r * DD + d0 + c4 * 4);
        float xs[4] = {v.x, v.y, v.z, v.w};
        bf16x4 hv, lv;
        #pragma unroll
        for (int q = 0; q < 4; ++q) {
            ushort_t hh, ll;
            split_bf16(xs[q], hh, ll);
            hv[q] = (short)hh; lv[q] = (short)ll;
        }
        if (u < 4) {
            *(bf16x4*)&Xh[r][c4 * 4] = hv;
            *(bf16x4*)&Xl[r][c4 * 4] = lv;
        } else {
            *(bf16x4*)&Yh[r][c4 * 4] = hv;
            *(bf16x4*)&Yl[r][c4 * 4] = lv;
        }
    }
    __syncthreads();

    #pragma unroll
    for (int kk = 0; kk < 2; ++kk) {
        const int co = kk * 32 + kg * 8;
        bf16x8 Ah[4], Al[4];
        #pragma unroll
        for (int mi = 0; mi < 4; ++mi) {
            int r = wm * 64 + mi * 16 + fr;
            Ah[mi] = *(const bf16x8*)&Xh[r][co];
            Al[mi] = *(const bf16x8*)&Xl[r][co];
        }
        #pragma unroll
        for (int ni = 0; ni < 2; ++ni) {
            int c = wn * 32 + ni * 16 + fr;
            bf16x8 Bh = *(const bf16x8*)&Yh[c][co];
            bf16x8 Bl = *(const bf16x8*)&Yl[c][co];
            #pragma unroll
            for (int mi = 0; mi < 4; ++mi) {
                acc[mi][ni] = __builtin_amdgcn_mfma_f32_16x16x32_bf16(Ah[mi], Bh, acc[mi][ni], 0, 0, 0);
                acc[mi][ni] = __builtin_amdgcn_mfma_f32_16x16x32_bf16(Ah[mi], Bl, acc[mi][ni], 0, 0, 0);
                acc[mi][ni] = __builtin_amdgcn_mfma_f32_16x16x32_bf16(Al[mi], Bh, acc[mi][ni], 0, 0, 0);
            }
        }
    }

    #pragma unroll
    for (int mi = 0; mi < 4; ++mi)
        #pragma unroll
        for (int ni = 0; ni < 2; ++ni) {
            int rbase = wm * 64 + mi * 16 + kg * 4;
            int ccol  = wn * 32 + ni * 16 + fr;
            #pragma unroll
            for (int rr = 0; rr < 4; ++rr)
                atomicAdd(&outp[(size_t)(rbase + rr) * KD + ccol], acc[mi][ni][rr]);
        }
}

// ---------------- K4: register-resident Gauss-Jordan inversion (SPD, no pivoting).
__global__ __launch_bounds__(512, 2) void invert_kernel(
    const float* __restrict__ AA, float* __restrict__ Hout)
{
    const int b = blockIdx.x, which = blockIdx.y;
    const float* src = AA + ((size_t)which * BB + b) * KD * KD;
    float* dst = Hout + ((size_t)which * BB + b) * KD * KD;

    __shared__ float rowbuf[2][KD];
    __shared__ float colbuf[2][KD];

    const int tid = threadIdx.x;
    const int rb = tid >> 5;
    const int cg = tid & 31;

    f32x4 Areg[8];
    #pragma unroll
    for (int r = 0; r < 8; ++r)
        Areg[r] = *(const f32x4*)(src + (size_t)(rb * 8 + r) * KD + cg * 4);

    if (rb == 0) *(f32x4*)&rowbuf[0][cg * 4] = Areg[0];
    if (cg == 0) {
        #pragma unroll
        for (int r = 0; r < 8; ++r) colbuf[0][rb * 8 + r] = Areg[r].x;
    }
    __syncthreads();

    for (int j = 0; j < KD; ++j) {
        const int cur = j & 1, nxt = cur ^ 1;
        const int jrb = j >> 3, jr = j & 7, jcg = j >> 2, jc = j & 3;
        const float pv = 1.0f / rowbuf[cur][j];
        const f32x4 orow = *(const f32x4*)&rowbuf[cur][cg * 4];
        const f32x4 prow = orow * pv;
        const bool mycg = (cg == jcg);
        const bool myrb = (rb == jrb);

        #pragma unroll
        for (int r = 0; r < 8; ++r) {
            const float cm = colbuf[cur][rb * 8 + r];
            const float cmul = -cm * pv;
            const bool piv = myrb && (r == jr);
            f32x4 nv;
            nv.x = piv ? prow.x : fmaf(cmul, orow.x, Areg[r].x);
            nv.y = piv ? prow.y : fmaf(cmul, orow.y, Areg[r].y);
            nv.z = piv ? prow.z : fmaf(cmul, orow.z, Areg[r].z);
            nv.w = piv ? prow.w : fmaf(cmul, orow.w, Areg[r].w);
            if (mycg) {
                const float fixv = piv ? pv : cmul;
                nv.x = (jc == 0) ? fixv : nv.x;
                nv.y = (jc == 1) ? fixv : nv.y;
                nv.z = (jc == 2) ? fixv : nv.z;
                nv.w = (jc == 3) ? fixv : nv.w;
            }
            Areg[r] = nv;
        }

        if (j + 1 < KD) {
            const int njrb = (j + 1) >> 3, njr = (j + 1) & 7;
            const int njcg = (j + 1) >> 2, njc = (j + 1) & 3;
            if (rb == njrb) {
                #pragma unroll
                for (int r = 0; r < 8; ++r)
                    if (r == njr) *(f32x4*)&rowbuf[nxt][cg * 4] = Areg[r];
            }
            if (cg == njcg) {
                #pragma unroll
                for (int r = 0; r < 8; ++r) {
                    const f32x4 a = Areg[r];
                    const float e = (njc == 0) ? a.x : (njc == 1) ? a.y : (njc == 2) ? a.z : a.w;
                    colbuf[nxt][rb * 8 + r] = e;
                }
            }
        }
        __syncthreads();
    }

    #pragma unroll
    for (int r = 0; r < 8; ++r)
        *(f32x4*)(dst + (size_t)(rb * 8 + r) * KD + cg * 4) = Areg[r];
}

// ---------------- K5: Neumann-series solve.
#define NTERMS 6
__global__ __launch_bounds__(512) void solve_kernel(
    const float* __restrict__ AAba, const float* __restrict__ lm_ab,
    const float* __restrict__ lm_ba, const float* __restrict__ Hmat,
    float* __restrict__ outp)
{
    const int b = blockIdx.x, cg = blockIdx.y, which = blockIdx.z;
    const float* Hm = Hmat + ((size_t)which * BB + b) * KD * KD;
    const float* lm = (which ? lm_ba : lm_ab) + (size_t)b * KD * KD;
    const float* Rs = AAba + (size_t)b * KD * KD;
    float* op = outp + ((size_t)which * BB + b) * KD * KD;
    const int i0 = cg * 32;

    __shared__ float Hs[KD][132];
    __shared__ float Zc[2][32][132];
    __shared__ float lms[32][132];

    const int tid = threadIdx.x;
    const int rq = tid & 31;
    const int cq = tid >> 5;

    #pragma unroll
    for (int u = 0; u < 8; ++u) {
        int idx = tid + u * 512;
        int d = idx >> 5, l4 = idx & 31;
        *(float4*)&Hs[d][l4 * 4] = *(const float4*)(Hm + (size_t)d * KD + l4 * 4);
    }
    #pragma unroll
    for (int u = 0; u < 8; ++u) {
        int idx = tid + u * 512;
        int ic = idx >> 7, l = idx & 127;
        lms[ic][l] = lm[(size_t)(i0 + ic) * KD + l];
    }
    if (which == 0) {
        #pragma unroll
        for (int u = 0; u < 8; ++u) {
            int idx = tid + u * 512;
            int ic = idx >> 7, d = idx & 127;
            Zc[0][ic][d] = Rs[(size_t)(i0 + ic) * KD + d];
        }
    } else {
        #pragma unroll
        for (int u = 0; u < 8; ++u) {
            int idx = tid + u * 512;
            int d = idx >> 5, ic = idx & 31;
            Zc[0][ic][d] = Rs[(size_t)d * KD + i0 + ic];
        }
    }
    __syncthreads();

    float xacc[4][2];
    #pragma unroll
    for (int rr = 0; rr < 4; ++rr) { xacc[rr][0] = 0.f; xacc[rr][1] = 0.f; }
    int cur = 0;
    for (int t = 0; t < NTERMS; ++t) {
        float zr[4][2];
        #pragma unroll
        for (int rr = 0; rr < 4; ++rr) { zr[rr][0] = 0.f; zr[rr][1] = 0.f; }
        #pragma unroll 8
        for (int d4 = 0; d4 < 32; ++d4) {
            float4 hv[4];
            #pragma unroll
            for (int dd = 0; dd < 4; ++dd)
                hv[dd] = *(const float4*)&Hs[d4 * 4 + dd][rq * 4];
            float4 wv[2];
            #pragma unroll
            for (int cc = 0; cc < 2; ++cc)
                wv[cc] = *(const float4*)&Zc[cur][cq * 2 + cc][d4 * 4];
            #pragma unroll
            for (int cc = 0; cc < 2; ++cc) {
                zr[0][cc] += hv[0].x * wv[cc].x + hv[1].x * wv[cc].y + hv[2].x * wv[cc].z + hv[3].x * wv[cc].w;
                zr[1][cc] += hv[0].y * wv[cc].x + hv[1].y * wv[cc].y + hv[2].y * wv[cc].z + hv[3].y * wv[cc].w;
                zr[2][cc] += hv[0].z * wv[cc].x + hv[1].z * wv[cc].y + hv[2].z * wv[cc].z + hv[3].z * wv[cc].w;
                zr[3][cc] += hv[0].w * wv[cc].x + hv[1].w * wv[cc].y + hv[2].w * wv[cc].z + hv[3].w * wv[cc].w;
            }
        }
        const float s = (t & 1) ? -1.f : 1.f;
        #pragma unroll
        for (int rr = 0; rr < 4; ++rr) {
            xacc[rr][0] += s * zr[rr][0];
            xacc[rr][1] += s * zr[rr][1];
        }
        if (t + 1 < NTERMS) {
            #pragma unroll
            for (int cc = 0; cc < 2; ++cc) {
                float4 lmv = *(const float4*)&lms[cq * 2 + cc][rq * 4];
                float4 w;
                w.x = lmv.x * zr[0][cc];
                w.y = lmv.y * zr[1][cc];
                w.z = lmv.z * zr[2][cc];
                w.w = lmv.w * zr[3][cc];
                *(float4*)&Zc[cur ^ 1][cq * 2 + cc][rq * 4] = w;
            }
            __syncthreads();
            cur ^= 1;
        }
    }
    #pragma unroll
    for (int cc = 0; cc < 2; ++cc) {
        float4 o;
        o.x = xacc[0][cc]; o.y = xacc[1][cc]; o.z = xacc[2][cc]; o.w = xacc[3][cc];
        *(float4*)(op + (size_t)(i0 + cq * 2 + cc) * KD + rq * 4) = o;
    }
}

extern "C" void kernel_launch(void* const* d_in, const int* in_sizes, int n_in,
                              void* d_out, int out_size, void* d_ws, size_t ws_size,
                              hipStream_t stream) {
    (void)in_sizes; (void)n_in; (void)out_size; (void)ws_size;
    const float* evals_a = (const float*)d_in[0];
    const float* pinv_a  = (const float*)d_in[1];
    const float* descr_a = (const float*)d_in[2];
    const float* evals_b = (const float*)d_in[3];
    const float* pinv_b  = (const float*)d_in[4];
    const float* descr_b = (const float*)d_in[5];
    float* out = (float*)d_out;
    float* ws = (float*)d_ws;

    const size_t SD = (size_t)BB * KD * DD;   // 524288
    const size_t MM = (size_t)BB * KD * KD;   // 262144
    float* sd_a  = ws;
    float* sd_b  = sd_a + SD;
    float* AA    = sd_b + SD;        // 3*MM: [0]=AA_aa [1]=AA_bb [2]=AA_ba
    float* lm_ab = AA + 3 * MM;
    float* lm_ba = lm_ab + MM;
    float* Hm    = lm_ba + MM;       // 2*MM

    // zero sd (proj atomics) and AA (gram atomics)
    hipMemsetAsync(sd_a, 0, (2 * SD + 3 * MM) * sizeof(float), stream);
    proj_kernel<<<dim3(BB, 2, 25), 1024, 0, stream>>>(pinv_a, descr_a, pinv_b, descr_b, sd_a, sd_b);
    mask_kernel<<<dim3(BB), 256, 0, stream>>>(evals_a, evals_b, lm_ab, lm_ba);
    gram_kernel<<<dim3(BB, 3, 4), 512, 0, stream>>>(sd_a, sd_b, AA);
    invert_kernel<<<dim3(BB, 2), 512, 0, stream>>>(AA, Hm);
    solve_kernel<<<dim3(BB, 4, 2), 512, 0, stream>>>(AA + 2 * MM, lm_ab, lm_ba, Hm, out);
}

// Round 9
// 287.206 us; speedup vs baseline: 1.3115x; 1.3115x over previous
//
#include <hip/hip_runtime.h>

#define BB 16
#define KD 128
#define ND 8000
#define DD 256
#define LMB 1000.0f

typedef __attribute__((ext_vector_type(8))) short bf16x8;
typedef __attribute__((ext_vector_type(4))) short bf16x4;
typedef __attribute__((ext_vector_type(4))) float f32x4;
typedef unsigned short ushort_t;

// exact split: x = hi + lo (hi = truncate-to-bf16, lo = truncate(x - hi);
// lo-truncation error <= 2^-16 |x| -- negligible vs the dropped al*bl term)
__device__ __forceinline__ void split_bf16(float x, ushort_t& h, ushort_t& l) {
    unsigned int bi = __float_as_uint(x);
    h = (ushort_t)(bi >> 16);
    float lo = x - __uint_as_float(bi & 0xFFFF0000u);
    l = (ushort_t)(__float_as_uint(lo) >> 16);
}

// RNE version for gram (cheap, small data)
__device__ __forceinline__ void split_bf16_rne(float x, ushort_t& h, ushort_t& l) {
    unsigned int bi = __float_as_uint(x);
    h = (ushort_t)(bi >> 16);
    float lo = x - __uint_as_float(bi & 0xFFFF0000u);
    unsigned int lb = __float_as_uint(lo);
    lb = lb + 0x7FFFu + ((lb >> 16) & 1u);
    l = (ushort_t)(lb >> 16);
}

// two f32x4 (k=0..3, k=4..7) -> bf16 hi/lo fragments
__device__ __forceinline__ void cvt8(f32x4 a, f32x4 b, bf16x8& h, bf16x8& l) {
    #pragma unroll
    for (int j = 0; j < 4; ++j) {
        ushort_t hh, ll;
        split_bf16(a[j], hh, ll); h[j] = (short)hh; l[j] = (short)ll;
        split_bf16(b[j], hh, ll); h[4 + j] = (short)hh; l[4 + j] = (short)ll;
    }
}

// async global->LDS, 16B per lane, lds dest = uniform base + lane*16
__device__ __forceinline__ void gll16(const float* g, float* l) {
    __builtin_amdgcn_global_load_lds(
        (const __attribute__((address_space(1))) void*)g,
        (__attribute__((address_space(3))) void*)l, 16, 0, 0);
}

// ---------------- K1: projection  sd[b][k][d] = sum_n pinv[b][k][n]*descr[b][d][n]
// Raw-fp32 async staging (global_load_lds w16, double-buffered, counted vmcnt(3)),
// split-bf16 conversion in the MFMA phase. XOR-swizzled source (c4 = slot^(row&7))
// + same XOR on ds_read (rule #21).
// CHUNK-INTERLEAVED slice map: slice s takes chunks c = s + 8*i (c in [0,250)).
// The 8 lockstep slices of a (b,which) read 8 consecutive 128B segments per row
// -> ~1KB contiguous per row in flight -> DRAM row-buffer hits (HBM-efficiency fix).
// grid (16 b, 2 which, 8 slices) = 256 blocks = 1/CU, 1024 thr = 16 waves (4x4),
// wave tile 32(k) x 64(d). 250 full chunks of 32 n: slices 0,1 do 32, rest 31.
#define ROWS 384      // KD + DD
#define CHF 32        // chunk width in floats (128B per row per chunk)
#define NSL 8
#define SBUF_FL 12288 // ROWS*CHF

__global__ __attribute__((amdgpu_flat_work_group_size(1024, 1024)))
void proj_kernel(
    const float* __restrict__ pinv_a, const float* __restrict__ descr_a,
    const float* __restrict__ pinv_b, const float* __restrict__ descr_b,
    float* __restrict__ sd_a, float* __restrict__ sd_b)
{
    const int b = blockIdx.x, which = blockIdx.y, s = blockIdx.z;
    const float* P  = (which ? pinv_b  : pinv_a)  + (size_t)b * KD * ND;
    const float* Dm = (which ? descr_b : descr_a) + (size_t)b * DD * ND;
    float* outp = (which ? sd_b : sd_a) + (size_t)b * KD * DD;

    __shared__ float Sbuf[2][SBUF_FL];

    const int tid = threadIdx.x;
    const int lane = tid & 63;
    const int wid = tid >> 6;                 // 0..15
    const int wm = wid >> 2, wn = wid & 3;    // wave tile: rows wm*32, cols wn*64
    const int fr = lane & 15;
    const int kg = lane >> 4;
    const int NC = (s < 2) ? 32 : 31;         // chunks for this slice (all full)

    // staging plan: 48 wave-instrs of 1KB; instr I = wid*3+u covers LDS rows [I*8, I*8+8)
    // lane: row = I*8 + (lane>>3), slot = lane&7; global col-group c4 = slot ^ (row&7)
    const float* gp[3];
    int lof[3];
    #pragma unroll
    for (int u = 0; u < 3; ++u) {
        int I = wid * 3 + u;
        int r = I * 8 + (lane >> 3);
        int c4 = (lane & 7) ^ (r & 7);
        const float* rowp = (r < KD) ? (P + (size_t)r * ND) : (Dm + (size_t)(r - KD) * ND);
        gp[u] = rowp + c4 * 4;
        lof[u] = I * 256;                     // float offset of this instr's 1KB window
    }

    f32x4 acc[2][4];
    #pragma unroll
    for (int i = 0; i < 2; ++i)
        #pragma unroll
        for (int j = 0; j < 4; ++j) acc[i][j] = (f32x4){0.f, 0.f, 0.f, 0.f};

    // prologue: stage chunk index 0 (global chunk s) -> buf 0
    #pragma unroll
    for (int u = 0; u < 3; ++u) gll16(gp[u] + s * CHF, &Sbuf[0][lof[u]]);

    for (int t = 0; t < NC; ++t) {
        const int buf = t & 1;
        if (t + 1 < NC) {
            const int noff = (s + NSL * (t + 1)) * CHF;
            #pragma unroll
            for (int u = 0; u < 3; ++u) gll16(gp[u] + noff, &Sbuf[buf ^ 1][lof[u]]);
            __builtin_amdgcn_sched_barrier(0);
            asm volatile("s_waitcnt vmcnt(3)" ::: "memory");   // wait chunk t only
        } else {
            __builtin_amdgcn_sched_barrier(0);
            asm volatile("s_waitcnt vmcnt(0)" ::: "memory");
        }
        __builtin_amdgcn_sched_barrier(0);
        __builtin_amdgcn_s_barrier();
        __builtin_amdgcn_sched_barrier(0);

        const float* base = &Sbuf[buf][0];
        #pragma unroll
        for (int ni = 0; ni < 4; ++ni) {
            const int rB = KD + wn * 64 + ni * 16 + fr;
            const int rb7 = rB & 7;
            f32x4 b0 = *(const f32x4*)(base + rB * CHF + (((2 * kg)     ^ rb7) << 2));
            f32x4 b1 = *(const f32x4*)(base + rB * CHF + (((2 * kg + 1) ^ rb7) << 2));
            bf16x8 Bh, Bl;
            cvt8(b0, b1, Bh, Bl);
            #pragma unroll
            for (int mi = 0; mi < 2; ++mi) {
                const int rA = wm * 32 + mi * 16 + fr;
                const int ra7 = rA & 7;
                f32x4 a0 = *(const f32x4*)(base + rA * CHF + (((2 * kg)     ^ ra7) << 2));
                f32x4 a1 = *(const f32x4*)(base + rA * CHF + (((2 * kg + 1) ^ ra7) << 2));
                bf16x8 Ah, Al;
                cvt8(a0, a1, Ah, Al);
                acc[mi][ni] = __builtin_amdgcn_mfma_f32_16x16x32_bf16(Ah, Bh, acc[mi][ni], 0, 0, 0);
                acc[mi][ni] = __builtin_amdgcn_mfma_f32_16x16x32_bf16(Ah, Bl, acc[mi][ni], 0, 0, 0);
                acc[mi][ni] = __builtin_amdgcn_mfma_f32_16x16x32_bf16(Al, Bh, acc[mi][ni], 0, 0, 0);
            }
        }
        __builtin_amdgcn_sched_barrier(0);
        __builtin_amdgcn_s_barrier();
    }

    // epilogue: C/D layout col=lane&15, row=(lane>>4)*4+reg (m89)
    #pragma unroll
    for (int mi = 0; mi < 2; ++mi)
        #pragma unroll
        for (int ni = 0; ni < 4; ++ni) {
            int rbase = wm * 32 + mi * 16 + kg * 4;
            int ccol  = wn * 64 + ni * 16 + fr;
            #pragma unroll
            for (int r = 0; r < 4; ++r)
                atomicAdd(&outp[(size_t)(rbase + r) * DD + ccol], acc[mi][ni][r]);
        }
}

// ---------------- K2: masks (lambda folded in)
__global__ __launch_bounds__(256) void mask_kernel(
    const float* __restrict__ ea_g, const float* __restrict__ eb_g,
    float* __restrict__ lm_ab, float* __restrict__ lm_ba)
{
    const int b = blockIdx.x, tid = threadIdx.x;
    __shared__ float ta[KD], ua[KD], tb[KD], ub[KD];
    __shared__ float red[256];
    float e = (tid < KD) ? ea_g[b * KD + tid] : eb_g[b * KD + (tid - KD)];
    red[tid] = e;
    __syncthreads();
    for (int s = 128; s > 0; s >>= 1) {
        if (tid < s) red[tid] = fmaxf(red[tid], red[tid + s]);
        __syncthreads();
    }
    float is = 1.0f / red[0];
    float g = e * is;
    float den = 1.0f / (g * g + 1.0f);
    if (tid < KD) { ta[tid] = g * den; ua[tid] = den; }
    else          { tb[tid - KD] = g * den; ub[tid - KD] = den; }
    __syncthreads();
    for (int idx = tid; idx < KD * KD; idx += 256) {
        int i = idx >> 7, kc = idx & 127;
        float re = tb[i] - ta[kc], im = ub[i] - ua[kc];
        lm_ab[(size_t)b * KD * KD + idx] = LMB * (re * re + im * im);
        float re2 = ta[i] - tb[kc], im2 = ua[i] - ub[kc];
        lm_ba[(size_t)b * KD * KD + idx] = LMB * (re2 * re2 + im2 * im2);
    }
}

// ---------------- K3: Grams via split-bf16 MFMA, d-split for parallelism.
#define GSTR 68
__global__ __launch_bounds__(512, 2) void gram_kernel(
    const float* __restrict__ sd_a, const float* __restrict__ sd_b,
    float* __restrict__ AA)
{
    const int b = blockIdx.x, m = blockIdx.y, dchunk = blockIdx.z;
    const float* X = (m == 0) ? sd_a : sd_b;
    const float* Y = (m == 2) ? sd_a : X;
    X += (size_t)b * KD * DD;
    Y += (size_t)b * KD * DD;
    float* outp = AA + ((size_t)m * BB + b) * KD * KD;
    const int d0 = dchunk * 64;

    __shared__ ushort_t Xh[KD][GSTR], Xl[KD][GSTR];
    __shared__ ushort_t Yh[KD][GSTR], Yl[KD][GSTR];

    const int tid = threadIdx.x;
    const int lane = tid & 63;
    const int wid = tid >> 6;
    const int wm = wid >> 2, wn = wid & 3;
    const int fr = lane & 15;
    const int kg = lane >> 4;

    f32x4 acc[4][2];
    #pragma unroll
    for (int i = 0; i < 4; ++i)
        #pragma unroll
        for (int j = 0; j < 2; ++j) acc[i][j] = (f32x4){0.f, 0.f, 0.f, 0.f};

    #pragma unroll
    for (int u = 0; u < 8; ++u) {
        int idx = tid + (u & 3) * 512;
        int r = idx >> 4, c4 = idx & 15;
        const float* src = (u < 4) ? X : Y;
        float4 v = *(const float4*)(src + (size_t)r * DD + d0 + c4 * 4);
        float xs[4] = {v.x, v.y, v.z, v.w};
        bf16x4 hv, lv;
        #pragma unroll
        for (int q = 0; q < 4; ++q) {
            ushort_t hh, ll;
            split_bf16_rne(xs[q], hh, ll);
            hv[q] = (short)hh; lv[q] = (short)ll;
        }
        if (u < 4) {
            *(bf16x4*)&Xh[r][c4 * 4] = hv;
            *(bf16x4*)&Xl[r][c4 * 4] = lv;
        } else {
            *(bf16x4*)&Yh[r][c4 * 4] = hv;
            *(bf16x4*)&Yl[r][c4 * 4] = lv;
        }
    }
    __syncthreads();

    #pragma unroll
    for (int kk = 0; kk < 2; ++kk) {
        const int co = kk * 32 + kg * 8;
        bf16x8 Ah[4], Al[4];
        #pragma unroll
        for (int mi = 0; mi < 4; ++mi) {
            int r = wm * 64 + mi * 16 + fr;
            Ah[mi] = *(const bf16x8*)&Xh[r][co];
            Al[mi] = *(const bf16x8*)&Xl[r][co];
        }
        #pragma unroll
        for (int ni = 0; ni < 2; ++ni) {
            int c = wn * 32 + ni * 16 + fr;
            bf16x8 Bh = *(const bf16x8*)&Yh[c][co];
            bf16x8 Bl = *(const bf16x8*)&Yl[c][co];
            #pragma unroll
            for (int mi = 0; mi < 4; ++mi) {
                acc[mi][ni] = __builtin_amdgcn_mfma_f32_16x16x32_bf16(Ah[mi], Bh, acc[mi][ni], 0, 0, 0);
                acc[mi][ni] = __builtin_amdgcn_mfma_f32_16x16x32_bf16(Ah[mi], Bl, acc[mi][ni], 0, 0, 0);
                acc[mi][ni] = __builtin_amdgcn_mfma_f32_16x16x32_bf16(Al[mi], Bh, acc[mi][ni], 0, 0, 0);
            }
        }
    }

    #pragma unroll
    for (int mi = 0; mi < 4; ++mi)
        #pragma unroll
        for (int ni = 0; ni < 2; ++ni) {
            int rbase = wm * 64 + mi * 16 + kg * 4;
            int ccol  = wn * 32 + ni * 16 + fr;
            #pragma unroll
            for (int rr = 0; rr < 4; ++rr)
                atomicAdd(&outp[(size_t)(rbase + rr) * KD + ccol], acc[mi][ni][rr]);
        }
}

// ---------------- K4: register-resident Gauss-Jordan inversion (SPD, no pivoting).
__global__ __launch_bounds__(512, 2) void invert_kernel(
    const float* __restrict__ AA, float* __restrict__ Hout)
{
    const int b = blockIdx.x, which = blockIdx.y;
    const float* src = AA + ((size_t)which * BB + b) * KD * KD;
    float* dst = Hout + ((size_t)which * BB + b) * KD * KD;

    __shared__ float rowbuf[2][KD];
    __shared__ float colbuf[2][KD];

    const int tid = threadIdx.x;
    const int rb = tid >> 5;
    const int cg = tid & 31;

    f32x4 Areg[8];
    #pragma unroll
    for (int r = 0; r < 8; ++r)
        Areg[r] = *(const f32x4*)(src + (size_t)(rb * 8 + r) * KD + cg * 4);

    if (rb == 0) *(f32x4*)&rowbuf[0][cg * 4] = Areg[0];
    if (cg == 0) {
        #pragma unroll
        for (int r = 0; r < 8; ++r) colbuf[0][rb * 8 + r] = Areg[r].x;
    }
    __syncthreads();

    for (int j = 0; j < KD; ++j) {
        const int cur = j & 1, nxt = cur ^ 1;
        const int jrb = j >> 3, jr = j & 7, jcg = j >> 2, jc = j & 3;
        const float pv = 1.0f / rowbuf[cur][j];
        const f32x4 orow = *(const f32x4*)&rowbuf[cur][cg * 4];
        const f32x4 prow = orow * pv;
        const bool mycg = (cg == jcg);
        const bool myrb = (rb == jrb);

        #pragma unroll
        for (int r = 0; r < 8; ++r) {
            const float cm = colbuf[cur][rb * 8 + r];
            const float cmul = -cm * pv;
            const bool piv = myrb && (r == jr);
            f32x4 nv;
            nv.x = piv ? prow.x : fmaf(cmul, orow.x, Areg[r].x);
            nv.y = piv ? prow.y : fmaf(cmul, orow.y, Areg[r].y);
            nv.z = piv ? prow.z : fmaf(cmul, orow.z, Areg[r].z);
            nv.w = piv ? prow.w : fmaf(cmul, orow.w, Areg[r].w);
            if (mycg) {
                const float fixv = piv ? pv : cmul;
                nv.x = (jc == 0) ? fixv : nv.x;
                nv.y = (jc == 1) ? fixv : nv.y;
                nv.z = (jc == 2) ? fixv : nv.z;
                nv.w = (jc == 3) ? fixv : nv.w;
            }
            Areg[r] = nv;
        }

        if (j + 1 < KD) {
            const int njrb = (j + 1) >> 3, njr = (j + 1) & 7;
            const int njcg = (j + 1) >> 2, njc = (j + 1) & 3;
            if (rb == njrb) {
                #pragma unroll
                for (int r = 0; r < 8; ++r)
                    if (r == njr) *(f32x4*)&rowbuf[nxt][cg * 4] = Areg[r];
            }
            if (cg == njcg) {
                #pragma unroll
                for (int r = 0; r < 8; ++r) {
                    const f32x4 a = Areg[r];
                    const float e = (njc == 0) ? a.x : (njc == 1) ? a.y : (njc == 2) ? a.z : a.w;
                    colbuf[nxt][rb * 8 + r] = e;
                }
            }
        }
        __syncthreads();
    }

    #pragma unroll
    for (int r = 0; r < 8; ++r)
        *(f32x4*)(dst + (size_t)(rb * 8 + r) * KD + cg * 4) = Areg[r];
}

// ---------------- K5: Neumann-series solve.
#define NTERMS 6
__global__ __launch_bounds__(512) void solve_kernel(
    const float* __restrict__ AAba, const float* __restrict__ lm_ab,
    const float* __restrict__ lm_ba, const float* __restrict__ Hmat,
    float* __restrict__ outp)
{
    const int b = blockIdx.x, cg = blockIdx.y, which = blockIdx.z;
    const float* Hm = Hmat + ((size_t)which * BB + b) * KD * KD;
    const float* lm = (which ? lm_ba : lm_ab) + (size_t)b * KD * KD;
    const float* Rs = AAba + (size_t)b * KD * KD;
    float* op = outp + ((size_t)which * BB + b) * KD * KD;
    const int i0 = cg * 32;

    __shared__ float Hs[KD][132];
    __shared__ float Zc[2][32][132];
    __shared__ float lms[32][132];

    const int tid = threadIdx.x;
    const int rq = tid & 31;
    const int cq = tid >> 5;

    #pragma unroll
    for (int u = 0; u < 8; ++u) {
        int idx = tid + u * 512;
        int d = idx >> 5, l4 = idx & 31;
        *(float4*)&Hs[d][l4 * 4] = *(const float4*)(Hm + (size_t)d * KD + l4 * 4);
    }
    #pragma unroll
    for (int u = 0; u < 8; ++u) {
        int idx = tid + u * 512;
        int ic = idx >> 7, l = idx & 127;
        lms[ic][l] = lm[(size_t)(i0 + ic) * KD + l];
    }
    if (which == 0) {
        #pragma unroll
        for (int u = 0; u < 8; ++u) {
            int idx = tid + u * 512;
            int ic = idx >> 7, d = idx & 127;
            Zc[0][ic][d] = Rs[(size_t)(i0 + ic) * KD + d];
        }
    } else {
        #pragma unroll
        for (int u = 0; u < 8; ++u) {
            int idx = tid + u * 512;
            int d = idx >> 5, ic = idx & 31;
            Zc[0][ic][d] = Rs[(size_t)d * KD + i0 + ic];
        }
    }
    __syncthreads();

    float xacc[4][2];
    #pragma unroll
    for (int rr = 0; rr < 4; ++rr) { xacc[rr][0] = 0.f; xacc[rr][1] = 0.f; }
    int cur = 0;
    for (int t = 0; t < NTERMS; ++t) {
        float zr[4][2];
        #pragma unroll
        for (int rr = 0; rr < 4; ++rr) { zr[rr][0] = 0.f; zr[rr][1] = 0.f; }
        #pragma unroll 8
        for (int d4 = 0; d4 < 32; ++d4) {
            float4 hv[4];
            #pragma unroll
            for (int dd = 0; dd < 4; ++dd)
                hv[dd] = *(const float4*)&Hs[d4 * 4 + dd][rq * 4];
            float4 wv[2];
            #pragma unroll
            for (int cc = 0; cc < 2; ++cc)
                wv[cc] = *(const float4*)&Zc[cur][cq * 2 + cc][d4 * 4];
            #pragma unroll
            for (int cc = 0; cc < 2; ++cc) {
                zr[0][cc] += hv[0].x * wv[cc].x + hv[1].x * wv[cc].y + hv[2].x * wv[cc].z + hv[3].x * wv[cc].w;
                zr[1][cc] += hv[0].y * wv[cc].x + hv[1].y * wv[cc].y + hv[2].y * wv[cc].z + hv[3].y * wv[cc].w;
                zr[2][cc] += hv[0].z * wv[cc].x + hv[1].z * wv[cc].y + hv[2].z * wv[cc].z + hv[3].z * wv[cc].w;
                zr[3][cc] += hv[0].w * wv[cc].x + hv[1].w * wv[cc].y + hv[2].w * wv[cc].z + hv[3].w * wv[cc].w;
            }
        }
        const float s = (t & 1) ? -1.f : 1.f;
        #pragma unroll
        for (int rr = 0; rr < 4; ++rr) {
            xacc[rr][0] += s * zr[rr][0];
            xacc[rr][1] += s * zr[rr][1];
        }
        if (t + 1 < NTERMS) {
            #pragma unroll
            for (int cc = 0; cc < 2; ++cc) {
                float4 lmv = *(const float4*)&lms[cq * 2 + cc][rq * 4];
                float4 w;
                w.x = lmv.x * zr[0][cc];
                w.y = lmv.y * zr[1][cc];
                w.z = lmv.z * zr[2][cc];
                w.w = lmv.w * zr[3][cc];
                *(float4*)&Zc[cur ^ 1][cq * 2 + cc][rq * 4] = w;
            }
            __syncthreads();
            cur ^= 1;
        }
    }
    #pragma unroll
    for (int cc = 0; cc < 2; ++cc) {
        float4 o;
        o.x = xacc[0][cc]; o.y = xacc[1][cc]; o.z = xacc[2][cc]; o.w = xacc[3][cc];
        *(float4*)(op + (size_t)(i0 + cq * 2 + cc) * KD + rq * 4) = o;
    }
}

extern "C" void kernel_launch(void* const* d_in, const int* in_sizes, int n_in,
                              void* d_out, int out_size, void* d_ws, size_t ws_size,
                              hipStream_t stream) {
    (void)in_sizes; (void)n_in; (void)out_size; (void)ws_size;
    const float* evals_a = (const float*)d_in[0];
    const float* pinv_a  = (const float*)d_in[1];
    const float* descr_a = (const float*)d_in[2];
    const float* evals_b = (const float*)d_in[3];
    const float* pinv_b  = (const float*)d_in[4];
    const float* descr_b = (const float*)d_in[5];
    float* out = (float*)d_out;
    float* ws = (float*)d_ws;

    const size_t SD = (size_t)BB * KD * DD;   // 524288
    const size_t MM = (size_t)BB * KD * KD;   // 262144
    float* sd_a  = ws;
    float* sd_b  = sd_a + SD;
    float* AA    = sd_b + SD;        // 3*MM: [0]=AA_aa [1]=AA_bb [2]=AA_ba
    float* lm_ab = AA + 3 * MM;
    float* lm_ba = lm_ab + MM;
    float* Hm    = lm_ba + MM;       // 2*MM

    // zero sd (proj atomics) and AA (gram atomics)
    hipMemsetAsync(sd_a, 0, (2 * SD + 3 * MM) * sizeof(float), stream);
    proj_kernel<<<dim3(BB, 2, NSL), 1024, 0, stream>>>(pinv_a, descr_a, pinv_b, descr_b, sd_a, sd_b);
    mask_kernel<<<dim3(BB), 256, 0, stream>>>(evals_a, evals_b, lm_ab, lm_ba);
    gram_kernel<<<dim3(BB, 3, 4), 512, 0, stream>>>(sd_a, sd_b, AA);
    invert_kernel<<<dim3(BB, 2), 512, 0, stream>>>(AA, Hm);
    solve_kernel<<<dim3(BB, 4, 2), 512, 0, stream>>>(AA + 2 * MM, lm_ab, lm_ba, Hm, out);
}